// Round 2
// baseline (107.026 us; speedup 1.0000x reference)
//
#include <hip/hip_runtime.h>
#include <math.h>

// out[t,b] = F(x[t,b]) — scalar function (zero-state LSTM cell x2 + linear).
// Build F-table (16384 entries over [-10,10]) each launch, then lerp.
//
// R7: single-dispatch fusion. rocprof showed per-iteration cost is dominated
// by harness-fixed work (1x 256MiB d_ws poison fill @40.3us + 13 restore
// dispatches); our marginal cost is ~2us per dispatch + GPU time. R5 used 3
// dispatches, R6 used 4 (+4.2us). This version uses ONE:
//   - per-block repack of w_ih2 -> f16x2 in LDS (w_ih2 is 42KB, L2-resident)
//   - per-block build of its 64 table entries (same math as R5)
//   - grid barrier WITHOUT cooperative launch: block b release-stores
//     done[b]=MAGIC (agent scope); all blocks spin on acquire loads until all
//     256 are MAGIC. Safe because the harness unconditionally re-poisons d_ws
//     every iteration (the 256MiB fill we measured), erasing stale MAGICs.
//     Co-residency: grid=256 blocks=256 CUs, __launch_bounds__(1024,4) caps
//     VGPR<=128 -> >=1 block/CU. Spin is iteration-capped: a protocol bug
//     fails verification instead of hanging.
//   - x float4 loads issued BEFORE the spin (latency hides under barrier),
//     lookup gathers from the L2/IF$-resident table after the acquire fence.

#define NTAB 16384
#define XMIN (-10.0f)
#define XMAX (10.0f)
#define MAGIC 0x7E57CAFEu

typedef _Float16 h2_t __attribute__((ext_vector_type(2)));

__device__ __forceinline__ float fexp2_(float x) { return __builtin_amdgcn_exp2f(x); }
__device__ __forceinline__ float frcp_(float x)  { return __builtin_amdgcn_rcpf(x); }
// sigmoid(z) = 1/(1+2^(-z*log2 e)) ; tanh(z) = 1 - 2/(1+2^(2z*log2 e))
__device__ __forceinline__ float fsig_(float z)  { return frcp_(1.0f + fexp2_(-1.44269504f * z)); }
__device__ __forceinline__ float ftanh_(float z) { return 1.0f - 2.0f * frcp_(1.0f + fexp2_(2.88539008f * z)); }

__device__ __forceinline__ float lerp_tab(float x, const float* __restrict__ t) {
    const float inv_h = (float)(NTAB - 1) / (XMAX - XMIN);
    float u = (x - XMIN) * inv_h;
    u = fminf(fmaxf(u, 0.0f), (float)(NTAB - 1) - 0.001f);
    int   i0 = (int)u;
    float f  = u - (float)i0;
    float t0 = t[i0];
    float t1 = t[i0 + 1];
    return fmaf(f, t1 - t0, t0);
}

// Live rows of w_ih2 (torch gate order i,f,g,o; f dead since c_prev=0):
// packed row r: r in [0,51) = i-gate j=r ; [51,102) = g-gate ; [102,153) = o-gate.
__global__ __launch_bounds__(1024, 4) void fused(
    const float* __restrict__ x,
    const float* __restrict__ w_ih1, const float* __restrict__ b_ih1, const float* __restrict__ b_hh1,
    const float* __restrict__ w_ih2, const float* __restrict__ b_ih2, const float* __restrict__ b_hh2,
    const float* __restrict__ w_lin, const float* __restrict__ b_lin,
    float* __restrict__ table, unsigned int* __restrict__ done,
    float* __restrict__ out, int n)
{
    __shared__ unsigned int Wp[153 * 26];   // 15912 B packed f16x2 weights
    __shared__ float B2s[153];              // pre-summed layer-2 biases
    __shared__ float h1s[51][64];           // h1 shared across waves, conflict-free
    __shared__ float sPart[16][64];

    const int tid  = threadIdx.x;
    const int lane = tid & 63;
    // readfirstlane: wave id provably uniform -> layer-1 weight addrs scalarize.
    const int wave = __builtin_amdgcn_readfirstlane(tid >> 6);
    const int bid  = blockIdx.x;
    const int nblk = (int)gridDim.x;        // 256

    // ---- Pre-issue this thread's lookup input (independent of the table) ----
    const int  n4     = n >> 2;
    const int  chunk4 = (n4 + nblk - 1) / nblk;         // 400 for n=409600
    const int  i4     = bid * chunk4 + tid;
    const bool act    = (tid < chunk4) && (i4 < n4);
    float4 xv = {0.f, 0.f, 0.f, 0.f};
    if (act) xv = ((const float4*)x)[i4];

    // ---- Repack layer-2 weights to f16x2 in LDS (4 strided iters) ----
    for (int g = tid; g < 153 * 26; g += 1024) {
        int r = g / 26;
        int p = g - r * 26;
        int src = (r < 51) ? r : r + 51;
        float a = w_ih2[src * 51 + 2 * p];
        float b = (2 * p + 1 < 51) ? w_ih2[src * 51 + 2 * p + 1] : 0.0f;
        h2_t h;
        h.x = (_Float16)a;   // RTE via v_cvt_f16_f32 (not pkrtz/RTZ: unbiased)
        h.y = (_Float16)b;
        Wp[g] = __builtin_bit_cast(unsigned int, h);
    }
    if (tid < 153) {
        int src = (tid < 51) ? tid : tid + 51;
        B2s[tid] = b_ih2[src] + b_hh2[src];
    }

    // ---- Phase 1: layer-1 for this block's 64 entries, rows over 16 waves ----
    const int   e  = bid * 64 + lane;                   // 256 blocks x 64 = NTAB
    const float xe = XMIN + (XMAX - XMIN) * ((float)e / (float)(NTAB - 1));
    for (int j = wave; j < 51; j += 16) {
        float gi = fmaf(xe, w_ih1[j],       b_ih1[j]       + b_hh1[j]);
        float gg = fmaf(xe, w_ih1[j + 102], b_ih1[j + 102] + b_hh1[j + 102]);
        float go = fmaf(xe, w_ih1[j + 153], b_ih1[j + 153] + b_hh1[j + 153]);
        float c  = fsig_(gi) * ftanh_(gg);
        h1s[j][lane] = fsig_(go) * ftanh_(c);
    }
    __syncthreads();    // covers h1s writes AND Wp/B2s writes

    // ---- Pack this lane's h1 vector to f16 pairs (26 VGPRs) ----
    h2_t h1p[26];
    #pragma unroll
    for (int p = 0; p < 26; ++p) {
        float a = h1s[2 * p][lane];
        float b = (2 * p + 1 < 51) ? h1s[2 * p + 1][lane] : 0.0f;
        h2_t h;
        h.x = (_Float16)a;
        h.y = (_Float16)b;
        h1p[p] = h;
    }

    // ---- Phase 2: each wave does 3-4 rows via v_dot2_f32_f16, weights from
    //      LDS (wave-uniform addr -> broadcast, conflict-free) ----
    float part = 0.0f;
    for (int j = wave; j < 51; j += 16) {
        const int bi = j * 26, bg = (51 + j) * 26, bo = (102 + j) * 26;
        float gi = B2s[j];
        float gg = B2s[51 + j];
        float go = B2s[102 + j];
        #pragma unroll
        for (int p = 0; p < 26; ++p) {
            gi = __builtin_amdgcn_fdot2(h1p[p], __builtin_bit_cast(h2_t, Wp[bi + p]), gi, false);
            gg = __builtin_amdgcn_fdot2(h1p[p], __builtin_bit_cast(h2_t, Wp[bg + p]), gg, false);
            go = __builtin_amdgcn_fdot2(h1p[p], __builtin_bit_cast(h2_t, Wp[bo + p]), go, false);
        }
        float c2  = fsig_(gi) * ftanh_(gg);
        float h2v = fsig_(go) * ftanh_(c2);
        part = fmaf(h2v, w_lin[j], part);
    }

    sPart[wave][lane] = part;
    __syncthreads();
    if (wave == 0) {
        float o = b_lin[0];
        #pragma unroll
        for (int w = 0; w < 16; ++w) o += sPart[w][lane];
        table[e] = o;
    }
    __syncthreads();   // compiler drains vmcnt(0) before s_barrier: table stores done

    if (tid == 0) {
        __threadfence();   // agent-scope writeback: table visible at coherence point
        __hip_atomic_store(&done[bid], MAGIC, __ATOMIC_RELEASE, __HIP_MEMORY_SCOPE_AGENT);
    }

    // ---- Grid barrier via magic flags. done[] lives in d_ws, which the
    //      harness re-poisons with a constant fill before every iteration,
    //      so stale MAGICs cannot leak across iterations. Capped spin. ----
    int it = 0;
    bool ok;
    do {
        unsigned int v = (tid < nblk)
            ? __hip_atomic_load(&done[tid], __ATOMIC_ACQUIRE, __HIP_MEMORY_SCOPE_AGENT)
            : MAGIC;
        ok = (v == MAGIC);
    } while (!__syncthreads_and((int)ok) && ++it < (1 << 20));

    // ---- Lookup for this block's contiguous output chunk ----
    if (act) {
        float4 r;
        r.x = lerp_tab(xv.x, table);
        r.y = lerp_tab(xv.y, table);
        r.z = lerp_tab(xv.z, table);
        r.w = lerp_tab(xv.w, table);
        ((float4*)out)[i4] = r;
    }
    // Generality guards (no-ops for n=409600): chunk4 > blockDim, and n%4 tail.
    const int hi = min((bid + 1) * chunk4, n4);
    for (int q = bid * chunk4 + 1024 + tid; q < hi; q += 1024) {
        float4 v4 = ((const float4*)x)[q];
        float4 r;
        r.x = lerp_tab(v4.x, table);
        r.y = lerp_tab(v4.y, table);
        r.z = lerp_tab(v4.z, table);
        r.w = lerp_tab(v4.w, table);
        ((float4*)out)[q] = r;
    }
    if (bid == nblk - 1) {
        for (int i = (n4 << 2) + tid; i < n; i += 1024) out[i] = lerp_tab(x[i], table);
    }
}

extern "C" void kernel_launch(void* const* d_in, const int* in_sizes, int n_in,
                              void* d_out, int out_size, void* d_ws, size_t ws_size,
                              hipStream_t stream) {
    const float* x     = (const float*)d_in[0];
    const float* w_ih1 = (const float*)d_in[1];
    // d_in[2] = w_hh1 (unused: h_prev = 0)
    const float* b_ih1 = (const float*)d_in[3];
    const float* b_hh1 = (const float*)d_in[4];
    const float* w_ih2 = (const float*)d_in[5];
    // d_in[6] = w_hh2 (unused)
    const float* b_ih2 = (const float*)d_in[7];
    const float* b_hh2 = (const float*)d_in[8];
    const float* w_lin = (const float*)d_in[9];
    const float* b_lin = (const float*)d_in[10];

    float* out = (float*)d_out;
    // d_ws layout (dwords): [0, NTAB) table | [NTAB, NTAB+256) done flags
    float*        table = (float*)d_ws;
    unsigned int* done  = (unsigned int*)d_ws + NTAB;
    const int n = in_sizes[0];     // T*B = 409600

    fused<<<256, 1024, 0, stream>>>(
        x, w_ih1, b_ih1, b_hh1, w_ih2, b_ih2, b_hh2, w_lin, b_lin,
        table, done, out, n);
}

// Round 4
// 91.966 us; speedup vs baseline: 1.1638x; 1.1638x over previous
//
#include <hip/hip_runtime.h>
#include <math.h>

// out[t,b] = F(x[t,b]) — scalar function (zero-state LSTM cell x2 + linear).
// Build F-table (16384 entries over [-10,10]) each launch, then lerp.
//
// R9 = R8 with the fence builtin fixed (__hip_atomic_fence doesn't exist;
// use __builtin_amdgcn_fence(__ATOMIC_ACQUIRE, "agent")).
//
// Single dispatch with a CHEAP grid barrier. R7's fused kernel spent ~37us
// spinning: 65,536 threads issued agent-scope ACQUIRE loads in a tight loop
// (each acquire = cache-invalidate + coherence round trip) -> contended-
// spinlock collapse. This version:
//   - only wave 0 of each block spins (other 15 waves park at s_barrier)
//   - RELAXED spin loads, ONE acquire fence after exit, s_sleep backoff
//   - arrival is one RELEASE magic-store per block (idempotent, init-free:
//     flags live in d_ws which the harness re-poisons with a 256MiB fill
//     every iteration — measured 40.3us — erasing stale MAGICs; and if the
//     fill were ever skipped, last iteration's table is still valid so an
//     early exit is harmless)
//   - table entries written with relaxed agent-scope stores (write-through),
//     so the release has no dirty L2 to drain
// Co-residency: 256 blocks = 256 CUs, 16 waves/block, VGPR<=128 -> all
// blocks resident; spin is round-capped so a protocol bug fails, not hangs.

#define NTAB 16384
#define XMIN (-10.0f)
#define XMAX (10.0f)
#define MAGIC 0x7E57CAFEu

typedef _Float16 h2_t __attribute__((ext_vector_type(2)));

__device__ __forceinline__ float fexp2_(float x) { return __builtin_amdgcn_exp2f(x); }
__device__ __forceinline__ float frcp_(float x)  { return __builtin_amdgcn_rcpf(x); }
// sigmoid(z) = 1/(1+2^(-z*log2 e)) ; tanh(z) = 1 - 2/(1+2^(2z*log2 e))
__device__ __forceinline__ float fsig_(float z)  { return frcp_(1.0f + fexp2_(-1.44269504f * z)); }
__device__ __forceinline__ float ftanh_(float z) { return 1.0f - 2.0f * frcp_(1.0f + fexp2_(2.88539008f * z)); }

__device__ __forceinline__ float lerp_tab(float x, const float* __restrict__ t) {
    const float inv_h = (float)(NTAB - 1) / (XMAX - XMIN);
    float u = (x - XMIN) * inv_h;
    u = fminf(fmaxf(u, 0.0f), (float)(NTAB - 1) - 0.001f);
    int   i0 = (int)u;
    float f  = u - (float)i0;
    float t0 = t[i0];
    float t1 = t[i0 + 1];
    return fmaf(f, t1 - t0, t0);
}

// Live rows of w_ih2 (torch gate order i,f,g,o; f dead since c_prev=0):
// packed row r: r in [0,51) = i-gate j=r ; [51,102) = g-gate ; [102,153) = o-gate.
__global__ __launch_bounds__(1024, 4) void fused(
    const float* __restrict__ x,
    const float* __restrict__ w_ih1, const float* __restrict__ b_ih1, const float* __restrict__ b_hh1,
    const float* __restrict__ w_ih2, const float* __restrict__ b_ih2, const float* __restrict__ b_hh2,
    const float* __restrict__ w_lin, const float* __restrict__ b_lin,
    float* __restrict__ table, unsigned int* __restrict__ flags,
    float* __restrict__ out, int n)
{
    __shared__ unsigned int Wp[153 * 26];   // 15912 B packed f16x2 weights
    __shared__ float B2s[153];              // pre-summed layer-2 biases
    __shared__ float h1s[51][64];           // h1 shared across waves, conflict-free
    __shared__ float sPart[16][64];

    const int tid  = threadIdx.x;
    const int lane = tid & 63;
    // readfirstlane: wave id provably uniform -> layer-1 weight addrs scalarize.
    const int wave = __builtin_amdgcn_readfirstlane(tid >> 6);
    const int bid  = blockIdx.x;
    const int nblk = (int)gridDim.x;        // 256

    // ---- Pre-issue this thread's lookup input (independent of the table) ----
    const int  n4     = n >> 2;
    const int  chunk4 = (n4 + nblk - 1) / nblk;         // 400 for n=409600
    const int  i4     = bid * chunk4 + tid;
    const bool act    = (tid < chunk4) && (i4 < n4);
    float4 xv = {0.f, 0.f, 0.f, 0.f};
    if (act) xv = ((const float4*)x)[i4];

    // ---- Repack layer-2 weights to f16x2 in LDS (4 strided iters) ----
    for (int g = tid; g < 153 * 26; g += 1024) {
        int r = g / 26;
        int p = g - r * 26;
        int src = (r < 51) ? r : r + 51;
        float a = w_ih2[src * 51 + 2 * p];
        float b = (2 * p + 1 < 51) ? w_ih2[src * 51 + 2 * p + 1] : 0.0f;
        h2_t h;
        h.x = (_Float16)a;   // RTE via v_cvt_f16_f32 (not pkrtz/RTZ: unbiased)
        h.y = (_Float16)b;
        Wp[g] = __builtin_bit_cast(unsigned int, h);
    }
    if (tid < 153) {
        int src = (tid < 51) ? tid : tid + 51;
        B2s[tid] = b_ih2[src] + b_hh2[src];
    }

    // ---- Phase 1: layer-1 for this block's 64 entries, rows over 16 waves ----
    const int   e  = bid * 64 + lane;                   // 256 blocks x 64 = NTAB
    const float xe = XMIN + (XMAX - XMIN) * ((float)e / (float)(NTAB - 1));
    for (int j = wave; j < 51; j += 16) {
        float gi = fmaf(xe, w_ih1[j],       b_ih1[j]       + b_hh1[j]);
        float gg = fmaf(xe, w_ih1[j + 102], b_ih1[j + 102] + b_hh1[j + 102]);
        float go = fmaf(xe, w_ih1[j + 153], b_ih1[j + 153] + b_hh1[j + 153]);
        float c  = fsig_(gi) * ftanh_(gg);
        h1s[j][lane] = fsig_(go) * ftanh_(c);
    }
    __syncthreads();    // covers h1s writes AND Wp/B2s writes

    // ---- Pack this lane's h1 vector to f16 pairs (26 VGPRs) ----
    h2_t h1p[26];
    #pragma unroll
    for (int p = 0; p < 26; ++p) {
        float a = h1s[2 * p][lane];
        float b = (2 * p + 1 < 51) ? h1s[2 * p + 1][lane] : 0.0f;
        h2_t h;
        h.x = (_Float16)a;
        h.y = (_Float16)b;
        h1p[p] = h;
    }

    // ---- Phase 2: each wave does 3-4 rows via v_dot2_f32_f16, weights from
    //      LDS (wave-uniform addr -> broadcast, conflict-free) ----
    float part = 0.0f;
    for (int j = wave; j < 51; j += 16) {
        const int bi = j * 26, bg = (51 + j) * 26, bo = (102 + j) * 26;
        float gi = B2s[j];
        float gg = B2s[51 + j];
        float go = B2s[102 + j];
        #pragma unroll
        for (int p = 0; p < 26; ++p) {
            gi = __builtin_amdgcn_fdot2(h1p[p], __builtin_bit_cast(h2_t, Wp[bi + p]), gi, false);
            gg = __builtin_amdgcn_fdot2(h1p[p], __builtin_bit_cast(h2_t, Wp[bg + p]), gg, false);
            go = __builtin_amdgcn_fdot2(h1p[p], __builtin_bit_cast(h2_t, Wp[bo + p]), go, false);
        }
        float c2  = fsig_(gi) * ftanh_(gg);
        float h2v = fsig_(go) * ftanh_(c2);
        part = fmaf(h2v, w_lin[j], part);
    }

    sPart[wave][lane] = part;
    __syncthreads();

    // ---- Wave 0: finish table entry, signal arrival, spin until all done ----
    if (wave == 0) {
        float o = b_lin[0];
        #pragma unroll
        for (int w = 0; w < 16; ++w) o += sPart[w][lane];
        // relaxed agent store: write-through, visible at coherence point,
        // leaves no dirty L2 line for the release to drain
        __hip_atomic_store(&table[e], o, __ATOMIC_RELAXED, __HIP_MEMORY_SCOPE_AGENT);

        if (lane == 0) {
            // release orders the table stores before the flag
            __hip_atomic_store(&flags[bid], MAGIC, __ATOMIC_RELEASE, __HIP_MEMORY_SCOPE_AGENT);
        }
        // 64 lanes x 4 flags each = all 256 blocks; RELAXED loads (no
        // invalidate storm), s_sleep backoff, round-capped.
        int rounds = 0;
        while (true) {
            bool r = true;
            #pragma unroll
            for (int q = 0; q < 4; ++q) {
                unsigned int v = __hip_atomic_load(&flags[lane + 64 * q],
                                                   __ATOMIC_RELAXED, __HIP_MEMORY_SCOPE_AGENT);
                r = r && (v == MAGIC);
            }
            if (__all((int)r) || ++rounds > (1 << 16)) break;
            __builtin_amdgcn_s_sleep(1);
        }
        // one acquire for the whole block (invalidates L1; per-CU, shared by
        // all 16 waves, which are still parked at the s_barrier below)
        __builtin_amdgcn_fence(__ATOMIC_ACQUIRE, "agent");
    }
    __syncthreads();   // other 15 waves were parked here, zero memory traffic

    // ---- Lookup for this block's contiguous output chunk ----
    if (act) {
        float4 r;
        r.x = lerp_tab(xv.x, table);
        r.y = lerp_tab(xv.y, table);
        r.z = lerp_tab(xv.z, table);
        r.w = lerp_tab(xv.w, table);
        ((float4*)out)[i4] = r;
    }
    // Generality guards (no-ops for n=409600): chunk4 > blockDim, and n%4 tail.
    const int hi = min((bid + 1) * chunk4, n4);
    for (int q = bid * chunk4 + 1024 + tid; q < hi; q += 1024) {
        float4 v4 = ((const float4*)x)[q];
        float4 r;
        r.x = lerp_tab(v4.x, table);
        r.y = lerp_tab(v4.y, table);
        r.z = lerp_tab(v4.z, table);
        r.w = lerp_tab(v4.w, table);
        ((float4*)out)[q] = r;
    }
    if (bid == nblk - 1) {
        for (int i = (n4 << 2) + tid; i < n; i += 1024) out[i] = lerp_tab(x[i], table);
    }
}

extern "C" void kernel_launch(void* const* d_in, const int* in_sizes, int n_in,
                              void* d_out, int out_size, void* d_ws, size_t ws_size,
                              hipStream_t stream) {
    const float* x     = (const float*)d_in[0];
    const float* w_ih1 = (const float*)d_in[1];
    // d_in[2] = w_hh1 (unused: h_prev = 0)
    const float* b_ih1 = (const float*)d_in[3];
    const float* b_hh1 = (const float*)d_in[4];
    const float* w_ih2 = (const float*)d_in[5];
    // d_in[6] = w_hh2 (unused)
    const float* b_ih2 = (const float*)d_in[7];
    const float* b_hh2 = (const float*)d_in[8];
    const float* w_lin = (const float*)d_in[9];
    const float* b_lin = (const float*)d_in[10];

    float* out = (float*)d_out;
    // d_ws layout (dwords): [0, NTAB) table | [NTAB, NTAB+256) arrival flags
    float*        table = (float*)d_ws;
    unsigned int* flags = (unsigned int*)d_ws + NTAB;
    const int n = in_sizes[0];     // T*B = 409600

    fused<<<256, 1024, 0, stream>>>(
        x, w_ih1, b_ih1, b_hh1, w_ih2, b_ih2, b_hh2, w_lin, b_lin,
        table, flags, out, n);
}

// Round 5
// 85.271 us; speedup vs baseline: 1.2551x; 1.0785x over previous
//
#include <hip/hip_runtime.h>
#include <math.h>

// out[t,b] = F(x[t,b]) — scalar function (zero-state LSTM cell x2 + linear).
// Build F-table (16384 entries over [-10,10]) each launch, then lerp.
//
// R10: 2-dispatch. History: R5 (3 dispatches) = 84.3us; R7/R9 single-dispatch
// with in-kernel grid barrier = 107/92us -> intra-kernel cross-XCD barrier
// costs ~12us (release visibility + poll round trips at the coherence point),
// MORE than the ~2.5us a kernel boundary costs. The kernel boundary IS the
// cheap grid barrier on this chip. Iteration budget is dominated by harness-
// fixed work (13 restore dispatches + 40us 256MiB d_ws poison fill, all
// serialized on the stream); our controllable slice is ~4.5us.
// This version folds the f16x2 weight repack INTO build_table as a per-block
// LDS repack (mechanics verified in R9): deletes one dispatch (~3us) and the
// global Wp round trip, costs ~0.3us of L2-resident w_ih2 re-reads.

#define NTAB 16384
#define XMIN (-10.0f)
#define XMAX (10.0f)

typedef _Float16 h2_t __attribute__((ext_vector_type(2)));

__device__ __forceinline__ float fexp2_(float x) { return __builtin_amdgcn_exp2f(x); }
__device__ __forceinline__ float frcp_(float x)  { return __builtin_amdgcn_rcpf(x); }
// sigmoid(z) = 1/(1+2^(-z*log2 e)) ; tanh(z) = 1 - 2/(1+2^(2z*log2 e))
__device__ __forceinline__ float fsig_(float z)  { return frcp_(1.0f + fexp2_(-1.44269504f * z)); }
__device__ __forceinline__ float ftanh_(float z) { return 1.0f - 2.0f * frcp_(1.0f + fexp2_(2.88539008f * z)); }

// Live rows of w_ih2 (torch gate order i,f,g,o; f dead since c_prev=0):
// packed row r: r in [0,51) = i-gate j=r ; [51,102) = g-gate ; [102,153) = o-gate.
__global__ __launch_bounds__(1024, 4) void build_table(
    const float* __restrict__ w_ih1, const float* __restrict__ b_ih1, const float* __restrict__ b_hh1,
    const float* __restrict__ w_ih2, const float* __restrict__ b_ih2, const float* __restrict__ b_hh2,
    const float* __restrict__ w_lin, const float* __restrict__ b_lin,
    float* __restrict__ table)
{
    __shared__ unsigned int Wp[153 * 26];   // 15912 B packed f16x2 weights
    __shared__ float B2s[153];              // pre-summed layer-2 biases
    __shared__ float h1s[51][64];           // h1 shared across waves, conflict-free
    __shared__ float sPart[16][64];

    const int tid  = threadIdx.x;
    const int lane = tid & 63;
    // readfirstlane: wave id provably uniform -> layer-1 weight addrs scalarize.
    const int wave = __builtin_amdgcn_readfirstlane(tid >> 6);

    // ---- Repack layer-2 weights to f16x2 in LDS (4 strided iters; w_ih2 is
    //      41.6KB, L2-resident after first block's fetch) ----
    for (int g = tid; g < 153 * 26; g += 1024) {
        int r = g / 26;
        int p = g - r * 26;
        int src = (r < 51) ? r : r + 51;
        float a = w_ih2[src * 51 + 2 * p];
        float b = (2 * p + 1 < 51) ? w_ih2[src * 51 + 2 * p + 1] : 0.0f;
        h2_t h;
        h.x = (_Float16)a;   // RTE via v_cvt_f16_f32 (not pkrtz/RTZ: unbiased)
        h.y = (_Float16)b;
        Wp[g] = __builtin_bit_cast(unsigned int, h);
    }
    if (tid < 153) {
        int src = (tid < 51) ? tid : tid + 51;
        B2s[tid] = b_ih2[src] + b_hh2[src];
    }

    // ---- Phase 1: layer-1 for this block's 64 entries, rows over 16 waves ----
    const int   e  = blockIdx.x * 64 + lane;            // 256 blocks x 64 = NTAB
    const float xe = XMIN + (XMAX - XMIN) * ((float)e / (float)(NTAB - 1));
    for (int j = wave; j < 51; j += 16) {
        float gi = fmaf(xe, w_ih1[j],       b_ih1[j]       + b_hh1[j]);
        float gg = fmaf(xe, w_ih1[j + 102], b_ih1[j + 102] + b_hh1[j + 102]);
        float go = fmaf(xe, w_ih1[j + 153], b_ih1[j + 153] + b_hh1[j + 153]);
        float c  = fsig_(gi) * ftanh_(gg);
        h1s[j][lane] = fsig_(go) * ftanh_(c);
    }
    __syncthreads();    // covers h1s writes AND Wp/B2s writes

    // ---- Pack this lane's h1 vector to f16 pairs (26 VGPRs) ----
    h2_t h1p[26];
    #pragma unroll
    for (int p = 0; p < 26; ++p) {
        float a = h1s[2 * p][lane];
        float b = (2 * p + 1 < 51) ? h1s[2 * p + 1][lane] : 0.0f;
        h2_t h;
        h.x = (_Float16)a;
        h.y = (_Float16)b;
        h1p[p] = h;
    }

    // ---- Phase 2: each wave does 3-4 rows via v_dot2_f32_f16, weights from
    //      LDS (wave-uniform addr -> broadcast, conflict-free) ----
    float part = 0.0f;
    for (int j = wave; j < 51; j += 16) {
        const int bi = j * 26, bg = (51 + j) * 26, bo = (102 + j) * 26;
        float gi = B2s[j];
        float gg = B2s[51 + j];
        float go = B2s[102 + j];
        #pragma unroll
        for (int p = 0; p < 26; ++p) {
            gi = __builtin_amdgcn_fdot2(h1p[p], __builtin_bit_cast(h2_t, Wp[bi + p]), gi, false);
            gg = __builtin_amdgcn_fdot2(h1p[p], __builtin_bit_cast(h2_t, Wp[bg + p]), gg, false);
            go = __builtin_amdgcn_fdot2(h1p[p], __builtin_bit_cast(h2_t, Wp[bo + p]), go, false);
        }
        float c2  = fsig_(gi) * ftanh_(gg);
        float h2v = fsig_(go) * ftanh_(c2);
        part = fmaf(h2v, w_lin[j], part);
    }

    sPart[wave][lane] = part;
    __syncthreads();
    if (wave == 0) {
        float o = b_lin[0];
        #pragma unroll
        for (int w = 0; w < 16; ++w) o += sPart[w][lane];
        table[e] = o;
    }
}

__device__ __forceinline__ float lerp_tab(float x, const float* __restrict__ t) {
    const float inv_h = (float)(NTAB - 1) / (XMAX - XMIN);
    float u = (x - XMIN) * inv_h;
    u = fminf(fmaxf(u, 0.0f), (float)(NTAB - 1) - 0.001f);
    int   i0 = (int)u;
    float f  = u - (float)i0;
    float t0 = t[i0];
    float t1 = t[i0 + 1];
    return fmaf(f, t1 - t0, t0);
}

__global__ __launch_bounds__(256) void lookup_kernel(
    const float* __restrict__ x, const float* __restrict__ table,
    float* __restrict__ out, int n)
{
    int i4 = blockIdx.x * 256 + threadIdx.x;
    int base = i4 * 4;
    if (base + 3 < n) {
        float4 xv = ((const float4*)x)[i4];
        float4 r;
        r.x = lerp_tab(xv.x, table);
        r.y = lerp_tab(xv.y, table);
        r.z = lerp_tab(xv.z, table);
        r.w = lerp_tab(xv.w, table);
        ((float4*)out)[i4] = r;
    } else {
        for (int i = base; i < n; ++i) out[i] = lerp_tab(x[i], table);
    }
}

extern "C" void kernel_launch(void* const* d_in, const int* in_sizes, int n_in,
                              void* d_out, int out_size, void* d_ws, size_t ws_size,
                              hipStream_t stream) {
    const float* x     = (const float*)d_in[0];
    const float* w_ih1 = (const float*)d_in[1];
    // d_in[2] = w_hh1 (unused: h_prev = 0)
    const float* b_ih1 = (const float*)d_in[3];
    const float* b_hh1 = (const float*)d_in[4];
    const float* w_ih2 = (const float*)d_in[5];
    // d_in[6] = w_hh2 (unused)
    const float* b_ih2 = (const float*)d_in[7];
    const float* b_hh2 = (const float*)d_in[8];
    const float* w_lin = (const float*)d_in[9];
    const float* b_lin = (const float*)d_in[10];

    float* out = (float*)d_out;
    float* table = (float*)d_ws;          // d_ws dwords [0, NTAB)
    const int n = in_sizes[0];            // T*B = 409600

    build_table<<<NTAB / 64, 1024, 0, stream>>>(
        w_ih1, b_ih1, b_hh1, w_ih2, b_ih2, b_hh2, w_lin, b_lin, table);

    const int n4 = (n + 3) / 4;
    lookup_kernel<<<(n4 + 255) / 256, 256, 0, stream>>>(x, table, out, n);
}